// Round 4
// baseline (258.519 us; speedup 1.0000x reference)
//
#include <hip/hip_runtime.h>

// CubicHermite2d: B=32, N=1024, axes are arange(N) => uniform knots, dx=1.
//
// out[b,k,p] = Hx(h0y*row_{Iy} + h2y*row_{Iy+1})(xs[p])
//            + h1y*(S[b,Iy+1,p]-S[b,Iy,p]) + h3y*(S[b,Iy+2,p]-S[b,Iy+1,p])
//
// R1: Hermite_x linear in row => stage ONE combined row (3 taps/output).
// R2: 4 batches/block (XCD-pinned) + nt-stores -> FETCH ~= compulsory.
// R4: batch-interleaved b128 gathers, swizzled. Conflicts 7.4M->3.1M but
//     kernel still ~90us; warm passes (zero fetch) also ~90us; no pipe >41%.
//     => latency/serialization-bound: two-phase barrier-coupled blocks,
//     ~3 resident blocks/CU can't hide the load->barrier->gather chain.
// R5 (this round): WAVE-INDEPENDENT, ZERO-BARRIER.
//     Each wave privately handles one (batch, k): own 4KB LDS row, lane owns
//     16 cols as 4 float4 chunks (LDS slot c*64+lane -> bank group lane%8,
//     conflict-free writes, no swizzle/transpose VALU). Gathers are wave-
//     local scalar reads (compiler fuses Ix/Ix+1 -> ds_read2_b32). No
//     __syncthreads at all; per-chunk load/compute/store keeps VGPR low so
//     residency (and latency hiding) can rise.

#define NGRID 1024
#define BATCH 32
#define KB    4      // batches per block = waves per block (BATCH = 8 XCDs * KB)

typedef float nfloat4 __attribute__((ext_vector_type(4)));

__global__ __launch_bounds__(256, 6) void hermite2d_fused(
    const float* __restrict__ signal,   // [B, N, N]
    const float* __restrict__ xs,       // [N]
    const float* __restrict__ ys,       // [N]
    float* __restrict__ out)            // [B, N(k), N(p)]
{
    const unsigned f = blockIdx.x;      // 0..8191
    const int xcd  = (int)(f & 7u);     // XCD-pinned batch group
    const int k    = (int)(f >> 3);     // y-query index 0..1023
    const int w    = threadIdx.x >> 6;  // wave id 0..3 -> batch b0+w
    const int lane = threadIdx.x & 63;
    const int b    = xcd * KB + w;

    __shared__ float crow[KB][NGRID];   // 4 KB per wave, wave-private

    // --- y-direction coefficients (uniform per block; scalar loads) ---
    const float qy = ys[k];
    int Iy = (int)floorf(qy);
    if (Iy < 0) Iy = 0;
    if (Iy > NGRID - 3) Iy = NGRID - 3;
    const float ty  = qy - (float)Iy;
    const float ty2 = ty * ty;
    const float ty3 = ty2 * ty;
    const float h0y = 1.0f - 3.0f * ty2 + 2.0f * ty3;
    const float h1y = ty - 2.0f * ty2 + ty3;
    const float h2y = 3.0f * ty2 - 2.0f * ty3;
    const float h3y = ty3 - ty2;

    const float4* src4 =
        (const float4*)(signal + ((size_t)b * NGRID + (size_t)Iy) * NGRID);

    // --- phase 1: per chunk c, lane handles float4 slot c*64+lane ---
    // LDS write slot = c*64+lane  -> bank group lane%8: conflict-free.
    float colp[KB][4];
    #pragma unroll
    for (int c = 0; c < 4; ++c) {
        const int s = c * 64 + lane;
        const float4 r0 = src4[s];
        const float4 r1 = src4[s + NGRID / 4];
        const float4 r2 = src4[s + NGRID / 2];

        float4 cc;
        cc.x = h0y * r0.x + h2y * r1.x;
        cc.y = h0y * r0.y + h2y * r1.y;
        cc.z = h0y * r0.z + h2y * r1.z;
        cc.w = h0y * r0.w + h2y * r1.w;
        ((float4*)crow[w])[s] = cc;

        colp[c][0] = h1y * (r1.x - r0.x) + h3y * (r2.x - r1.x);
        colp[c][1] = h1y * (r1.y - r0.y) + h3y * (r2.y - r1.y);
        colp[c][2] = h1y * (r1.z - r0.z) + h3y * (r2.z - r1.z);
        colp[c][3] = h1y * (r1.w - r0.w) + h3y * (r2.w - r1.w);
    }

    // NO __syncthreads(): each wave reads only its own LDS region; the
    // compiler orders the wave's own ds_write -> ds_read via lgkmcnt.

    // --- phase 2: per chunk, gather 3 taps/output from wave-private row ---
    float* orow = out + ((size_t)b * NGRID + (size_t)k) * NGRID;
    #pragma unroll
    for (int c = 0; c < 4; ++c) {
        const int s = c * 64 + lane;
        const float4 q4 = ((const float4*)xs)[s];
        float4 res;
        #pragma unroll
        for (int j = 0; j < 4; ++j) {
            const float q = ((const float*)&q4)[j];
            int Ix = (int)floorf(q);
            if (Ix < 0) Ix = 0;
            if (Ix > NGRID - 3) Ix = NGRID - 3;
            const float tx = q - (float)Ix;
            const float t2 = tx * tx;
            const float t3 = t2 * tx;
            const float w0 = 1.0f - tx - t2 + t3;
            const float w1 = tx + 2.0f * (t2 - t3);
            const float w2 = t3 - t2;
            const float c0 = crow[w][Ix];
            const float c1 = crow[w][Ix + 1];
            const float c2 = crow[w][Ix + 2];
            ((float*)&res)[j] = w0 * c0 + w1 * c1 + w2 * c2 + colp[c][j];
        }
        __builtin_nontemporal_store(*(const nfloat4*)&res, (nfloat4*)orow + s);
    }
}

extern "C" void kernel_launch(void* const* d_in, const int* in_sizes, int n_in,
                              void* d_out, int out_size, void* d_ws, size_t ws_size,
                              hipStream_t stream) {
    // inputs: 0=xaxis[N], 1=yaxis[N], 2=signal[B,N,N], 3=xs[N], 4=ys[N] (all f32)
    const float* signal = (const float*)d_in[2];
    const float* xs     = (const float*)d_in[3];
    const float* ys     = (const float*)d_in[4];
    float* out          = (float*)d_out;

    dim3 grid(NGRID * (BATCH / KB));    // 8192 blocks, 1D: (f&7)=XCD, (f>>3)=k
    hermite2d_fused<<<grid, 256, 0, stream>>>(signal, xs, ys, out);
}